// Round 2
// baseline (1224.341 us; speedup 1.0000x reference)
//
#include <hip/hip_runtime.h>
#include <stdint.h>

#define EPSF 1e-5f

// problem sizes
#define NB 32
#define NC 256
#define NMID 128
#define NGROW 32
#define HW 3136      // 56*56
#define WD 56
#define BCHW 25690112   // 32*256*3136
#define BMHW 12845056   // 32*128*3136

__device__ __forceinline__ float clip127(float v) {
    return fminf(fmaxf(v, -128.f), 127.f);
}

// ---------------- prep kernels ----------------
__global__ void prep1(const float* __restrict__ g, const float* __restrict__ be,
                      const float* __restrict__ mn, const float* __restrict__ vr,
                      const float* __restrict__ s_in_p, const float* __restrict__ s_out_p,
                      float* __restrict__ wA, float* __restrict__ bA, float* __restrict__ misc,
                      float* __restrict__ out, int out_last) {
    __shared__ float red[256];
    int t = threadIdx.x;
    float s_in = s_in_p[0];
    float w = __fmul_rn(g[t], __frsqrt_rn(__fadd_rn(vr[t], EPSF)));
    float bb = __fsub_rn(be[t], __fmul_rn(mn[t], w));
    red[t] = fabsf(w);
    __syncthreads();
    for (int s = 128; s > 0; s >>= 1) { if (t < s) red[t] = fmaxf(red[t], red[t + s]); __syncthreads(); }
    float ws = __fdiv_rn(red[0], 127.f);
    wA[t] = clip127(rintf(__fdiv_rn(w, ws)));
    float sA = __fmul_rn(ws, s_in);
    bA[t] = rintf(__fdiv_rn(bb, sA));
    if (t == 0) { misc[0] = sA; out[out_last] = s_out_p[0]; }
}

__global__ void prep2(const float* __restrict__ g, const float* __restrict__ be,
                      const float* __restrict__ mn, const float* __restrict__ vr,
                      const float* __restrict__ w1, const float* __restrict__ s1_p,
                      float* __restrict__ w1T, float* __restrict__ b1, float* __restrict__ sB) {
    __shared__ float red[256];
    int t = threadIdx.x, m = blockIdx.x;
    float f = __fmul_rn(g[m], __frsqrt_rn(__fadd_rn(vr[m], EPSF)));
    float wf = __fmul_rn(w1[m * 256 + t], f);
    red[t] = fabsf(wf);
    __syncthreads();
    for (int s = 128; s > 0; s >>= 1) { if (t < s) red[t] = fmaxf(red[t], red[t + s]); __syncthreads(); }
    float ws = __fdiv_rn(red[0], 127.f);
    w1T[t * 128 + m] = clip127(rintf(__fdiv_rn(wf, ws)));
    if (t == 0) {
        float s1 = s1_p[0];
        float bf = __fsub_rn(be[m], __fmul_rn(mn[m], f));
        float sb = __fmul_rn(ws, s1);
        b1[m] = rintf(__fdiv_rn(bf, sb));
        sB[m] = sb;
    }
}

__global__ void prep3(const float* __restrict__ w2, const float* __restrict__ s2_p,
                      float* __restrict__ w2f, float* __restrict__ sC) {
    __shared__ float red[256];
    int t = threadIdx.x, o = blockIdx.x;
    float mx = 0.f;
    for (int k = t; k < 1152; k += 256) mx = fmaxf(mx, fabsf(w2[o * 1152 + k]));
    red[t] = mx;
    __syncthreads();
    for (int s = 128; s > 0; s >>= 1) { if (t < s) red[t] = fmaxf(red[t], red[t + s]); __syncthreads(); }
    float ws = __fdiv_rn(red[0], 127.f);
    for (int k = t; k < 1152; k += 256)
        w2f[o * 1152 + k] = clip127(rintf(__fdiv_rn(w2[o * 1152 + k], ws)));
    if (t == 0) sC[o] = __fmul_rn(ws, s2_p[0]);
}

// ---------------- stage A: BN quant + passthrough output ----------------
__global__ __launch_bounds__(256) void stageA(const float* __restrict__ batch,
        const float* __restrict__ sfp, const float* __restrict__ s1p, const float* __restrict__ soutp,
        const float* __restrict__ wA, const float* __restrict__ bA, const float* __restrict__ misc,
        int8_t* __restrict__ a8, float* __restrict__ out) {
    int i4 = blockIdx.x * 256 + threadIdx.x;
    if (i4 >= BCHW / 4) return;
    int base = i4 * 4;
    int b = base / 802816;
    int rem = base - b * 802816;
    int c = rem / 3136;
    int pos = rem - c * 3136;
    float s_in = sfp[0], s1 = s1p[0], s_out = soutp[0], sA = misc[0];
    float wc = wA[c], bc = bA[c];
    float4 v = *(const float4*)(batch + base);
    float vv[4] = {v.x, v.y, v.z, v.w};
    uint32_t pk = 0;
    float ov[4];
    for (int j = 0; j < 4; j++) {
        float xi = __fdiv_rn(vv[j], s_in);
        float tt = __fadd_rn(__fmul_rn(xi, wc), bc);
        float x = __fmul_rn(tt, sA);
        x = fmaxf(x, 0.f);
        float q = __fdiv_rn(x, s1);
        int ai = (int)clip127(rintf(q));
        pk |= ((uint32_t)(uint8_t)ai) << (8 * j);
        float qo = __fdiv_rn(vv[j], s_out);
        ov[j] = __fmul_rn(clip127(rintf(qo)), s_out);
    }
    *(uint32_t*)(a8 + base) = pk;
    int obase = (b * 288 + c) * 3136 + pos;
    *(float4*)(out + obase) = make_float4(ov[0], ov[1], ov[2], ov[3]);
}

// ---------------- conv1: 1x1, 256->128, GEMM-ish ----------------
__global__ __launch_bounds__(256) void conv1k(const int8_t* __restrict__ a8,
        const float* __restrict__ w1T, const float* __restrict__ b1, const float* __restrict__ sB,
        const float* __restrict__ s2p, int8_t* __restrict__ b8) {
    __shared__ float alds[256 * 64];
    int t = threadIdx.x;
    int blk = blockIdx.x;          // 32 * 49
    int b = blk / 49, tile = blk % 49;
    int hw0 = tile * 64;
    const int8_t* abase = a8 + b * 802816 + hw0;
    for (int it = 0; it < 16; it++) {
        int id = it * 256 + t;       // 0..4095
        int c = id >> 4, p4 = (id & 15) << 2;
        int word = *(const int*)(abase + c * 3136 + p4);
        float4 fv;
        fv.x = (float)(int8_t)(word);
        fv.y = (float)(int8_t)(word >> 8);
        fv.z = (float)(int8_t)(word >> 16);
        fv.w = (float)(int8_t)(word >> 24);
        *(float4*)(&alds[c * 64 + p4]) = fv;
    }
    __syncthreads();
    int pt = t & 15, mt = t >> 4;
    const float* wbase = w1T + mt * 8;
    float acc[4][8];
    for (int i = 0; i < 4; i++) for (int j = 0; j < 8; j++) acc[i][j] = 0.f;
    for (int c = 0; c < 256; c++) {
        float4 a4 = *(float4*)(&alds[c * 64 + pt * 4]);
        float4 w0 = *(const float4*)(wbase + c * 128);
        float4 w1v = *(const float4*)(wbase + c * 128 + 4);
        float av[4] = {a4.x, a4.y, a4.z, a4.w};
        float wv[8] = {w0.x, w0.y, w0.z, w0.w, w1v.x, w1v.y, w1v.z, w1v.w};
        for (int i = 0; i < 4; i++)
            for (int j = 0; j < 8; j++)
                acc[i][j] = fmaf(av[i], wv[j], acc[i][j]);
    }
    float s2 = s2p[0];
    for (int j = 0; j < 8; j++) {
        int m = mt * 8 + j;
        float bb = b1[m], sb = sB[m];
        uint32_t pk = 0;
        for (int i = 0; i < 4; i++) {
            float y = __fadd_rn(acc[i][j], bb);
            float x = __fmul_rn(y, sb);
            x = fmaxf(x, 0.f);
            float q = __fdiv_rn(x, s2);
            int bi = (int)clip127(rintf(q));
            pk |= ((uint32_t)(uint8_t)bi) << (8 * i);
        }
        *(uint32_t*)(b8 + (b * 128 + m) * 3136 + hw0 + pt * 4) = pk;
    }
}

// ---------------- conv2: 3x3 SAME, 128->32 ----------------
__global__ __launch_bounds__(256) void conv2k(const int8_t* __restrict__ b8,
        const float* __restrict__ w2f, const float* __restrict__ sC,
        const float* __restrict__ soutp, float* __restrict__ out) {
    int tid = blockIdx.x * 256 + threadIdx.x;   // 802816 total
    int xq = tid % 14;
    int r1 = tid / 14;
    int y = r1 % 56;
    int r2 = r1 / 56;
    int o = r2 % 32;
    int b = r2 / 32;
    int x0 = xq * 4;
    float acc[4] = {0.f, 0.f, 0.f, 0.f};
    const int8_t* inb = b8 + b * 401408;
    const float* wb = w2f + o * 1152;
    for (int c = 0; c < 128; c++) {
        const int8_t* inc = inb + c * 3136;
        const float* wc = wb + c * 9;
        for (int dy = 0; dy < 3; dy++) {
            int yy = y + dy - 1;
            if ((unsigned)yy < 56u) {
                const int8_t* row = inc + yy * 56;
                float f[6];
                for (int k = 0; k < 6; k++) {
                    int xx = x0 - 1 + k;
                    f[k] = ((unsigned)xx < 56u) ? (float)row[xx] : 0.f;
                }
                float w0 = wc[dy * 3], w1 = wc[dy * 3 + 1], w2 = wc[dy * 3 + 2];
                for (int j = 0; j < 4; j++)
                    acc[j] = fmaf(f[j], w0, fmaf(f[j + 1], w1, fmaf(f[j + 2], w2, acc[j])));
            }
        }
    }
    float scC = sC[o], s_out = soutp[0];
    int obase = (b * 288 + 256 + o) * 3136 + y * 56 + x0;
    float ov[4];
    for (int j = 0; j < 4; j++) {
        float x = __fmul_rn(acc[j], scC);
        float q = __fdiv_rn(x, s_out);
        ov[j] = __fmul_rn(clip127(rintf(q)), s_out);
    }
    *(float4*)(out + obase) = make_float4(ov[0], ov[1], ov[2], ov[3]);
}

extern "C" void kernel_launch(void* const* d_in, const int* in_sizes, int n_in,
                              void* d_out, int out_size, void* d_ws, size_t ws_size,
                              hipStream_t stream) {
    const float* batch = (const float*)d_in[0];
    const float* s_in  = (const float*)d_in[1];
    const float* bn1g  = (const float*)d_in[2];
    const float* bn1b  = (const float*)d_in[3];
    const float* bn1m  = (const float*)d_in[4];
    const float* bn1v  = (const float*)d_in[5];
    const float* w1    = (const float*)d_in[6];
    const float* bn2g  = (const float*)d_in[7];
    const float* bn2b  = (const float*)d_in[8];
    const float* bn2m  = (const float*)d_in[9];
    const float* bn2v  = (const float*)d_in[10];
    const float* w2    = (const float*)d_in[11];
    const float* s1    = (const float*)d_in[12];
    const float* s2    = (const float*)d_in[13];
    const float* s_out = (const float*)d_in[14];
    float* out = (float*)d_out;
    char* ws = (char*)d_ws;

    int8_t* a8  = (int8_t*)ws;                     // 25,690,112 B
    int8_t* b8  = (int8_t*)(ws + 25690112);        // 12,845,056 B
    float* w1T  = (float*)(ws + 38535168);         // 131,072 B
    float* w2f  = (float*)(ws + 38666240);         // 147,456 B
    float* wA   = (float*)(ws + 38813696);         // 1 KB
    float* bA   = (float*)(ws + 38814720);         // 1 KB
    float* b1   = (float*)(ws + 38815744);         // 512 B
    float* sB   = (float*)(ws + 38816256);         // 512 B
    float* sC   = (float*)(ws + 38816768);         // 128 B
    float* misc = (float*)(ws + 38816896);         // 64 B

    prep1<<<1, 256, 0, stream>>>(bn1g, bn1b, bn1m, bn1v, s_in, s_out, wA, bA, misc, out, out_size - 1);
    prep2<<<128, 256, 0, stream>>>(bn2g, bn2b, bn2m, bn2v, w1, s1, w1T, b1, sB);
    prep3<<<32, 256, 0, stream>>>(w2, s2, w2f, sC);
    stageA<<<25088, 256, 0, stream>>>(batch, s_in, s1, s_out, wA, bA, misc, a8, out);
    conv1k<<<1568, 256, 0, stream>>>(a8, w1T, b1, sB, s2, b8);
    conv2k<<<3136, 256, 0, stream>>>(b8, w2f, sC, s_out, out);
}

// Round 10
// 186.919 us; speedup vs baseline: 6.5501x; 6.5501x over previous
//
#include <hip/hip_runtime.h>
#include <stdint.h>

#define EPSF 1e-5f

// problem sizes
#define NB 32
#define NC 256
#define NMID 128
#define NGROW 32
#define HW 3136      // 56*56
#define WD 56
#define BCHW 25690112   // 32*256*3136
#define BMHW 12845056   // 32*128*3136

typedef int i32x4 __attribute__((ext_vector_type(4)));

__device__ __forceinline__ float clip127(float v) {
    return fminf(fmaxf(v, -128.f), 127.f);
}

// ---------------- prep kernels ----------------
__global__ void prep1(const float* __restrict__ g, const float* __restrict__ be,
                      const float* __restrict__ mn, const float* __restrict__ vr,
                      const float* __restrict__ s_in_p, const float* __restrict__ s_out_p,
                      float* __restrict__ wA, float* __restrict__ bA, float* __restrict__ misc,
                      float* __restrict__ out, int out_last) {
    __shared__ float red[256];
    int t = threadIdx.x;
    float s_in = s_in_p[0];
    float w = __fmul_rn(g[t], __frsqrt_rn(__fadd_rn(vr[t], EPSF)));
    float bb = __fsub_rn(be[t], __fmul_rn(mn[t], w));
    red[t] = fabsf(w);
    __syncthreads();
    for (int s = 128; s > 0; s >>= 1) { if (t < s) red[t] = fmaxf(red[t], red[t + s]); __syncthreads(); }
    float ws = __fdiv_rn(red[0], 127.f);
    wA[t] = clip127(rintf(__fdiv_rn(w, ws)));
    float sA = __fmul_rn(ws, s_in);
    bA[t] = rintf(__fdiv_rn(bb, sA));
    if (t == 0) { misc[0] = sA; out[out_last] = s_out_p[0]; }
}

__global__ void prep2(const float* __restrict__ g, const float* __restrict__ be,
                      const float* __restrict__ mn, const float* __restrict__ vr,
                      const float* __restrict__ w1, const float* __restrict__ s1_p,
                      float* __restrict__ w1T, float* __restrict__ b1, float* __restrict__ sB) {
    __shared__ float red[256];
    int t = threadIdx.x, m = blockIdx.x;
    float f = __fmul_rn(g[m], __frsqrt_rn(__fadd_rn(vr[m], EPSF)));
    float wf = __fmul_rn(w1[m * 256 + t], f);
    red[t] = fabsf(wf);
    __syncthreads();
    for (int s = 128; s > 0; s >>= 1) { if (t < s) red[t] = fmaxf(red[t], red[t + s]); __syncthreads(); }
    float ws = __fdiv_rn(red[0], 127.f);
    w1T[t * 128 + m] = clip127(rintf(__fdiv_rn(wf, ws)));
    if (t == 0) {
        float s1 = s1_p[0];
        float bf = __fsub_rn(be[m], __fmul_rn(mn[m], f));
        float sb = __fmul_rn(ws, s1);
        b1[m] = rintf(__fdiv_rn(bf, sb));
        sB[m] = sb;
    }
}

// weights for conv2, int8, tap-major K layout: w8A[o][tap*128 + c]
__global__ void prep3(const float* __restrict__ w2, const float* __restrict__ s2_p,
                      int8_t* __restrict__ w8A, float* __restrict__ sC) {
    __shared__ float red[256];
    int t = threadIdx.x, o = blockIdx.x;
    float mx = 0.f;
    for (int k = t; k < 1152; k += 256) mx = fmaxf(mx, fabsf(w2[o * 1152 + k]));
    red[t] = mx;
    __syncthreads();
    for (int s = 128; s > 0; s >>= 1) { if (t < s) red[t] = fmaxf(red[t], red[t + s]); __syncthreads(); }
    float ws = __fdiv_rn(red[0], 127.f);
    for (int k = t; k < 1152; k += 256) {
        int c = k / 9, tap = k % 9;
        float q = clip127(rintf(__fdiv_rn(w2[o * 1152 + k], ws)));
        w8A[o * 1152 + tap * 128 + c] = (int8_t)(int)q;
    }
    if (t == 0) sC[o] = __fmul_rn(ws, s2_p[0]);
}

// ---------------- stage A: BN quant + passthrough output ----------------
__global__ __launch_bounds__(256) void stageA(const float* __restrict__ batch,
        const float* __restrict__ sfp, const float* __restrict__ s1p, const float* __restrict__ soutp,
        const float* __restrict__ wA, const float* __restrict__ bA, const float* __restrict__ misc,
        int8_t* __restrict__ a8, float* __restrict__ out) {
    int i4 = blockIdx.x * 256 + threadIdx.x;
    if (i4 >= BCHW / 4) return;
    int base = i4 * 4;
    int b = base / 802816;
    int rem = base - b * 802816;
    int c = rem / 3136;
    int pos = rem - c * 3136;
    float s_in = sfp[0], s1 = s1p[0], s_out = soutp[0], sA = misc[0];
    float wc = wA[c], bc = bA[c];
    float4 v = *(const float4*)(batch + base);
    float vv[4] = {v.x, v.y, v.z, v.w};
    uint32_t pk = 0;
    float ov[4];
    for (int j = 0; j < 4; j++) {
        float xi = __fdiv_rn(vv[j], s_in);
        float tt = __fadd_rn(__fmul_rn(xi, wc), bc);
        float x = __fmul_rn(tt, sA);
        x = fmaxf(x, 0.f);
        float q = __fdiv_rn(x, s1);
        int ai = (int)clip127(rintf(q));
        pk |= ((uint32_t)(uint8_t)ai) << (8 * j);
        float qo = __fdiv_rn(vv[j], s_out);
        ov[j] = __fmul_rn(clip127(rintf(qo)), s_out);
    }
    *(uint32_t*)(a8 + base) = pk;
    int obase = (b * 288 + c) * 3136 + pos;
    *(float4*)(out + obase) = make_float4(ov[0], ov[1], ov[2], ov[3]);
}

// ---------------- conv1: 1x1, 256->128, f32 GEMM; writes swizzled NHWC int8 ----
// b8T[(b*3136 + hw)*128 + (c ^ sw(x))], sw(x) = (((x+1)&7)<<4)
__global__ __launch_bounds__(256) void conv1k(const int8_t* __restrict__ a8,
        const float* __restrict__ w1T, const float* __restrict__ b1, const float* __restrict__ sB,
        const float* __restrict__ s2p, int8_t* __restrict__ b8T) {
    __shared__ float alds[256 * 64];
    int t = threadIdx.x;
    int blk = blockIdx.x;          // 32 * 49
    int b = blk / 49, tile = blk % 49;
    int hw0 = tile * 64;
    const int8_t* abase = a8 + b * 802816 + hw0;
    for (int it = 0; it < 16; it++) {
        int id = it * 256 + t;       // 0..4095
        int c = id >> 4, p4 = (id & 15) << 2;
        int word = *(const int*)(abase + c * 3136 + p4);
        float4 fv;
        fv.x = (float)(int8_t)(word);
        fv.y = (float)(int8_t)(word >> 8);
        fv.z = (float)(int8_t)(word >> 16);
        fv.w = (float)(int8_t)(word >> 24);
        *(float4*)(&alds[c * 64 + p4]) = fv;
    }
    __syncthreads();
    int pt = t & 15, mt = t >> 4;
    const float* wbase = w1T + mt * 8;
    float acc[4][8];
    for (int i = 0; i < 4; i++) for (int j = 0; j < 8; j++) acc[i][j] = 0.f;
    for (int c = 0; c < 256; c++) {
        float4 a4 = *(float4*)(&alds[c * 64 + pt * 4]);
        float4 w0 = *(const float4*)(wbase + c * 128);
        float4 w1v = *(const float4*)(wbase + c * 128 + 4);
        float av[4] = {a4.x, a4.y, a4.z, a4.w};
        float wv[8] = {w0.x, w0.y, w0.z, w0.w, w1v.x, w1v.y, w1v.z, w1v.w};
        for (int i = 0; i < 4; i++)
            for (int j = 0; j < 8; j++)
                acc[i][j] = fmaf(av[i], wv[j], acc[i][j]);
    }
    float s2 = s2p[0];
    float bb[8], sb[8];
    for (int j = 0; j < 8; j++) { bb[j] = b1[mt * 8 + j]; sb[j] = sB[mt * 8 + j]; }
    for (int i = 0; i < 4; i++) {
        int hw = hw0 + pt * 4 + i;
        int x = hw % 56;
        uint32_t lo = 0, hi = 0;
        for (int j = 0; j < 8; j++) {
            float y = __fadd_rn(acc[i][j], bb[j]);
            float xq = __fmul_rn(y, sb[j]);
            xq = fmaxf(xq, 0.f);
            float q = __fdiv_rn(xq, s2);
            int bi = (int)clip127(rintf(q));
            uint32_t u = (uint32_t)(uint8_t)bi;
            if (j < 4) lo |= u << (8 * j); else hi |= u << (8 * (j - 4));
        }
        int sw = (((x + 1) & 7) << 4);
        size_t off = ((size_t)(b * 3136 + hw)) * 128 + (size_t)((mt * 8) ^ sw);
        *(uint32_t*)(b8T + off) = lo;
        *(uint32_t*)(b8T + off + 4) = hi;
    }
}

// ---------------- conv2: 3x3 SAME, 128->32, int8 MFMA implicit GEMM ----------
// block: 2 output rows x 32 o x 56 px. LDS [4 rows][64 x'][128 c] int8, x'=x_in+1,
// swizzled c-offset (c ^ ((x'&7)<<4)) baked into b8T by conv1.
__global__ __launch_bounds__(256) void conv2k(const int8_t* __restrict__ b8T,
        const int8_t* __restrict__ w8A, const float* __restrict__ sC,
        const float* __restrict__ soutp, float* __restrict__ out) {
    __shared__ __align__(16) int8_t lds[4 * 64 * 128];   // 32 KB
    int t = threadIdx.x;
    int blk = blockIdx.x;               // 32 b * 28 ytiles
    int b = blk / 28, tile = blk % 28;
    int y0 = tile * 2;
    int wid = t >> 6, lane = t & 63;

    // zero edge columns: x'=0 and x'=57..63, all 4 rows
    {
        int r = wid, idx = lane;
        i32x4 z = {0, 0, 0, 0};
        int addr;
        if (idx < 8) addr = r * 8192 + idx * 16;
        else {
            int xp = 57 + (idx - 8) / 8, sub = (idx - 8) & 7;
            addr = r * 8192 + xp * 128 + sub * 16;
        }
        *(i32x4*)(lds + addr) = z;
    }
    // stage input rows (wave w -> LDS row w)
    {
        int r = wid;
        int y_in = y0 - 1 + r;
        if ((unsigned)y_in < 56u) {
            const int8_t* src = b8T + ((size_t)(b * 3136 + y_in * 56)) * 128;
            for (int it = 0; it < 7; it++) {
                i32x4 v = *(const i32x4*)(src + it * 1024 + lane * 16);
                *(i32x4*)(lds + r * 8192 + 128 + it * 1024 + lane * 16) = v;
            }
        } else {
            i32x4 z = {0, 0, 0, 0};
            for (int it = 0; it < 8; it++)
                *(i32x4*)(lds + r * 8192 + it * 1024 + lane * 16) = z;
        }
    }
    __syncthreads();

    int m = wid & 1, r_out = wid >> 1;
    int o_base = m * 16;
    // preload A fragments: lane holds A[o=o_base+(lane&15)][k=(lane>>4)*16 + j]
    i32x4 afr[18];
    const int8_t* abase = w8A + (size_t)(o_base + (lane & 15)) * 1152 + (lane >> 4) * 16;
    #pragma unroll
    for (int ks = 0; ks < 18; ks++)
        afr[ks] = *(const i32x4*)(abase + ks * 64);

    i32x4 acc[4];
    #pragma unroll
    for (int nt = 0; nt < 4; nt++) acc[nt] = (i32x4){0, 0, 0, 0};
    int c_lane = (lane >> 4) * 16;
    int xl = lane & 15;

    #pragma unroll
    for (int ks = 0; ks < 18; ks++) {
        int dy = ks / 6, rest = ks % 6;
        int dx = rest >> 1, c0 = (rest & 1) * 64;
        int r = r_out + dy;
        #pragma unroll
        for (int nt = 0; nt < 4; nt++) {
            int x_out = nt * 16 + xl;
            int xp = x_out + dx; if (xp > 63) xp = 63;
            int caddr = (c0 + c_lane) ^ ((xp & 7) << 4);
            i32x4 bfr = *(const i32x4*)(lds + r * 8192 + xp * 128 + caddr);
            acc[nt] = __builtin_amdgcn_mfma_i32_16x16x64_i8(afr[ks], bfr, acc[nt], 0, 0, 0);
        }
    }

    // epilogue: C/D layout col=lane&15 (pixel), row=(lane>>4)*4+reg (o)
    float s_out = soutp[0];
    int orow = o_base + ((lane >> 4) << 2);
    float sc[4];
    #pragma unroll
    for (int reg = 0; reg < 4; reg++) sc[reg] = sC[orow + reg];
    int y = y0 + r_out;
    size_t outb = ((size_t)b * 288 + 256 + orow) * 3136 + (size_t)y * 56;
    #pragma unroll
    for (int nt = 0; nt < 4; nt++) {
        int x_out = nt * 16 + xl;
        if (x_out < 56) {
            #pragma unroll
            for (int reg = 0; reg < 4; reg++) {
                float xf = __fmul_rn((float)acc[nt][reg], sc[reg]);
                float q = __fdiv_rn(xf, s_out);
                float val = __fmul_rn(clip127(rintf(q)), s_out);
                out[outb + (size_t)reg * 3136 + x_out] = val;
            }
        }
    }
}

extern "C" void kernel_launch(void* const* d_in, const int* in_sizes, int n_in,
                              void* d_out, int out_size, void* d_ws, size_t ws_size,
                              hipStream_t stream) {
    const float* batch = (const float*)d_in[0];
    const float* s_in  = (const float*)d_in[1];
    const float* bn1g  = (const float*)d_in[2];
    const float* bn1b  = (const float*)d_in[3];
    const float* bn1m  = (const float*)d_in[4];
    const float* bn1v  = (const float*)d_in[5];
    const float* w1    = (const float*)d_in[6];
    const float* bn2g  = (const float*)d_in[7];
    const float* bn2b  = (const float*)d_in[8];
    const float* bn2m  = (const float*)d_in[9];
    const float* bn2v  = (const float*)d_in[10];
    const float* w2    = (const float*)d_in[11];
    const float* s1    = (const float*)d_in[12];
    const float* s2    = (const float*)d_in[13];
    const float* s_out = (const float*)d_in[14];
    float* out = (float*)d_out;
    char* ws = (char*)d_ws;

    int8_t* a8  = (int8_t*)ws;                     // 25,690,112 B
    int8_t* b8T = (int8_t*)(ws + 25690112);        // 12,845,056 B (swizzled NHWC)
    float* w1T  = (float*)(ws + 38535168);         // 131,072 B
    int8_t* w8A = (int8_t*)(ws + 38666240);        // 36,864 B
    float* wA   = (float*)(ws + 38703104);         // 1 KB
    float* bA   = (float*)(ws + 38704128);         // 1 KB
    float* b1   = (float*)(ws + 38705152);         // 512 B
    float* sB   = (float*)(ws + 38705664);         // 512 B
    float* sC   = (float*)(ws + 38706176);         // 128 B
    float* misc = (float*)(ws + 38706304);         // 64 B

    prep1<<<1, 256, 0, stream>>>(bn1g, bn1b, bn1m, bn1v, s_in, s_out, wA, bA, misc, out, out_size - 1);
    prep2<<<128, 256, 0, stream>>>(bn2g, bn2b, bn2m, bn2v, w1, s1, w1T, b1, sB);
    prep3<<<32, 256, 0, stream>>>(w2, s2, w8A, sC);
    stageA<<<25088, 256, 0, stream>>>(batch, s_in, s1, s_out, wA, bA, misc, a8, out);
    conv1k<<<1568, 256, 0, stream>>>(a8, w1T, b1, sB, s2, b8T);
    conv2k<<<896, 256, 0, stream>>>(b8T, w8A, sC, s_out, out);
}

// Round 16
// 109.068 us; speedup vs baseline: 11.2254x; 1.7138x over previous
//
#include <hip/hip_runtime.h>
#include <stdint.h>

#define EPSF 1e-5f

// problem sizes
#define NB 32
#define NC 256
#define NMID 128
#define NGROW 32
#define HW 3136      // 56*56
#define WD 56
#define BCHW 25690112   // 32*256*3136
#define BMHW 12845056   // 32*128*3136

typedef int i32x4 __attribute__((ext_vector_type(4)));

__device__ __forceinline__ float clip127(float v) {
    return fminf(fmaxf(v, -128.f), 127.f);
}

// ---------------- prep kernels ----------------
__global__ void prep1(const float* __restrict__ g, const float* __restrict__ be,
                      const float* __restrict__ mn, const float* __restrict__ vr,
                      const float* __restrict__ s_in_p, const float* __restrict__ s_out_p,
                      float* __restrict__ wA, float* __restrict__ bA, float* __restrict__ misc,
                      float* __restrict__ out, int out_last) {
    __shared__ float red[256];
    int t = threadIdx.x;
    float s_in = s_in_p[0];
    float w = __fmul_rn(g[t], __frsqrt_rn(__fadd_rn(vr[t], EPSF)));
    float bb = __fsub_rn(be[t], __fmul_rn(mn[t], w));
    red[t] = fabsf(w);
    __syncthreads();
    for (int s = 128; s > 0; s >>= 1) { if (t < s) red[t] = fmaxf(red[t], red[t + s]); __syncthreads(); }
    float ws = __fdiv_rn(red[0], 127.f);
    wA[t] = clip127(rintf(__fdiv_rn(w, ws)));
    float sA = __fmul_rn(ws, s_in);
    bA[t] = rintf(__fdiv_rn(bb, sA));
    if (t == 0) { misc[0] = sA; out[out_last] = s_out_p[0]; }
}

// conv1 weights folded with bn2 -> int8 row-major w1i8[m][c], bias b1, scale sB
__global__ void prep2(const float* __restrict__ g, const float* __restrict__ be,
                      const float* __restrict__ mn, const float* __restrict__ vr,
                      const float* __restrict__ w1, const float* __restrict__ s1_p,
                      int8_t* __restrict__ w1i8, float* __restrict__ b1, float* __restrict__ sB) {
    __shared__ float red[256];
    int t = threadIdx.x, m = blockIdx.x;
    float f = __fmul_rn(g[m], __frsqrt_rn(__fadd_rn(vr[m], EPSF)));
    float wf = __fmul_rn(w1[m * 256 + t], f);
    red[t] = fabsf(wf);
    __syncthreads();
    for (int s = 128; s > 0; s >>= 1) { if (t < s) red[t] = fmaxf(red[t], red[t + s]); __syncthreads(); }
    float ws = __fdiv_rn(red[0], 127.f);
    float q = clip127(rintf(__fdiv_rn(wf, ws)));
    w1i8[m * 256 + t] = (int8_t)(int)q;
    if (t == 0) {
        float s1 = s1_p[0];
        float bf = __fsub_rn(be[m], __fmul_rn(mn[m], f));
        float sb = __fmul_rn(ws, s1);
        b1[m] = rintf(__fdiv_rn(bf, sb));
        sB[m] = sb;
    }
}

// weights for conv2, int8, tap-major K layout: w8A[o][tap*128 + c]
__global__ void prep3(const float* __restrict__ w2, const float* __restrict__ s2_p,
                      int8_t* __restrict__ w8A, float* __restrict__ sC) {
    __shared__ float red[256];
    int t = threadIdx.x, o = blockIdx.x;
    float mx = 0.f;
    for (int k = t; k < 1152; k += 256) mx = fmaxf(mx, fabsf(w2[o * 1152 + k]));
    red[t] = mx;
    __syncthreads();
    for (int s = 128; s > 0; s >>= 1) { if (t < s) red[t] = fmaxf(red[t], red[t + s]); __syncthreads(); }
    float ws = __fdiv_rn(red[0], 127.f);
    for (int k = t; k < 1152; k += 256) {
        int c = k / 9, tap = k % 9;
        float q = clip127(rintf(__fdiv_rn(w2[o * 1152 + k], ws)));
        w8A[o * 1152 + tap * 128 + c] = (int8_t)(int)q;
    }
    if (t == 0) sC[o] = __fmul_rn(ws, s2_p[0]);
}

// ---------------- stage A: BN quant + passthrough output ----------------
__global__ __launch_bounds__(256) void stageA(const float* __restrict__ batch,
        const float* __restrict__ sfp, const float* __restrict__ s1p, const float* __restrict__ soutp,
        const float* __restrict__ wA, const float* __restrict__ bA, const float* __restrict__ misc,
        int8_t* __restrict__ a8, float* __restrict__ out) {
    int i4 = blockIdx.x * 256 + threadIdx.x;
    if (i4 >= BCHW / 4) return;
    int base = i4 * 4;
    int b = base / 802816;
    int rem = base - b * 802816;
    int c = rem / 3136;
    int pos = rem - c * 3136;
    float s_in = sfp[0], s1 = s1p[0], s_out = soutp[0], sA = misc[0];
    float wc = wA[c], bc = bA[c];
    float4 v = *(const float4*)(batch + base);
    float vv[4] = {v.x, v.y, v.z, v.w};
    uint32_t pk = 0;
    float ov[4];
    for (int j = 0; j < 4; j++) {
        float xi = __fdiv_rn(vv[j], s_in);
        float tt = __fadd_rn(__fmul_rn(xi, wc), bc);
        float x = __fmul_rn(tt, sA);
        x = fmaxf(x, 0.f);
        float q = __fdiv_rn(x, s1);
        int ai = (int)clip127(rintf(q));
        pk |= ((uint32_t)(uint8_t)ai) << (8 * j);
        float qo = __fdiv_rn(vv[j], s_out);
        ov[j] = __fmul_rn(clip127(rintf(qo)), s_out);
    }
    *(uint32_t*)(a8 + base) = pk;
    int obase = (b * 288 + c) * 3136 + pos;
    *(float4*)(out + obase) = make_float4(ov[0], ov[1], ov[2], ov[3]);
}

// ---------------- conv1: 1x1, 256->128, int8 MFMA; writes swizzled NHWC int8 ----
// LDS: a8 tile pixel-major [64 px][256 c] int8, swizzle c ^ ((px&15)<<4).
// Output b8T[(b*3136 + hw)*128 + (m ^ sw(x))], sw(x) = (((x+1)&7)<<4)  (conv2k contract).
__global__ __launch_bounds__(256) void conv1k(const int8_t* __restrict__ a8,
        const int8_t* __restrict__ w1i8, const float* __restrict__ b1, const float* __restrict__ sB,
        const float* __restrict__ s2p, int8_t* __restrict__ b8T) {
    __shared__ __align__(16) int8_t lds[64 * 256];   // 16 KB
    int t = threadIdx.x;
    int blk = blockIdx.x;          // 32 b * 49 tiles
    int b = blk / 49, tile = blk % 49;
    int hw0 = tile * 64;

    // stage: read a8 channel-major (coalesced u32), byte-scatter to pixel-major swizzled LDS
    #pragma unroll 4
    for (int it = 0; it < 16; it++) {
        int c = it * 16 + (t >> 4);
        int p4 = (t & 15) * 4;
        uint32_t w = *(const uint32_t*)(a8 + (size_t)(b * 256 + c) * 3136 + hw0 + p4);
        #pragma unroll
        for (int j = 0; j < 4; j++) {
            int px = p4 + j;
            lds[px * 256 + (c ^ ((px & 15) << 4))] = (int8_t)(w >> (8 * j));
        }
    }
    __syncthreads();

    int wid = t >> 6, lane = t & 63;
    int px_base = wid * 16;
    int px = px_base + (lane & 15);
    int ksl = (lane >> 4);                 // k-slice within MFMA (0..3), 16 bytes each

    // B fragments: 16 px x 256 K, per wave (held in regs, read once)
    i32x4 bf[4];
    #pragma unroll
    for (int kk = 0; kk < 4; kk++) {
        int coff = (kk * 64 + ksl * 16) ^ ((px & 15) << 4);
        bf[kk] = *(const i32x4*)(lds + px * 256 + coff);
    }

    float s2 = s2p[0];
    int hw = hw0 + px;
    int x = hw - (hw / 56) * 56;
    int sw = (((x + 1) & 7) << 4);
    size_t outrow = (size_t)(b * 3136 + hw) * 128;

    #pragma unroll
    for (int ot = 0; ot < 8; ot++) {
        // A fragments: weights for o = ot*16 + (lane&15), K contiguous
        const int8_t* wb = w1i8 + (size_t)(ot * 16 + (lane & 15)) * 256 + ksl * 16;
        i32x4 acc = (i32x4){0, 0, 0, 0};
        #pragma unroll
        for (int kk = 0; kk < 4; kk++) {
            i32x4 af = *(const i32x4*)(wb + kk * 64);
            acc = __builtin_amdgcn_mfma_i32_16x16x64_i8(af, bf[kk], acc, 0, 0, 0);
        }
        // epilogue: lane holds px (col) x o rows m0..m0+3
        int m0 = ot * 16 + ksl * 4;
        uint32_t pk = 0;
        #pragma unroll
        for (int reg = 0; reg < 4; reg++) {
            float y = __fadd_rn((float)acc[reg], b1[m0 + reg]);
            float xq = __fmul_rn(y, sB[m0 + reg]);
            xq = fmaxf(xq, 0.f);
            float q = __fdiv_rn(xq, s2);
            int bi = (int)clip127(rintf(q));
            pk |= ((uint32_t)(uint8_t)bi) << (8 * reg);
        }
        *(uint32_t*)(b8T + outrow + (size_t)(m0 ^ sw)) = pk;
    }
}

// ---------------- conv2: 3x3 SAME, 128->32, int8 MFMA implicit GEMM ----------
// block: 2 output rows x 32 o x 56 px. LDS [4 rows][64 x'][128 c] int8, x'=x_in+1,
// swizzled c-offset (c ^ ((x'&7)<<4)) baked into b8T by conv1.
__global__ __launch_bounds__(256) void conv2k(const int8_t* __restrict__ b8T,
        const int8_t* __restrict__ w8A, const float* __restrict__ sC,
        const float* __restrict__ soutp, float* __restrict__ out) {
    __shared__ __align__(16) int8_t lds[4 * 64 * 128];   // 32 KB
    int t = threadIdx.x;
    int blk = blockIdx.x;               // 32 b * 28 ytiles
    int b = blk / 28, tile = blk % 28;
    int y0 = tile * 2;
    int wid = t >> 6, lane = t & 63;

    // zero edge columns: x'=0 and x'=57..63, all 4 rows
    {
        int r = wid, idx = lane;
        i32x4 z = {0, 0, 0, 0};
        int addr;
        if (idx < 8) addr = r * 8192 + idx * 16;
        else {
            int xp = 57 + (idx - 8) / 8, sub = (idx - 8) & 7;
            addr = r * 8192 + xp * 128 + sub * 16;
        }
        *(i32x4*)(lds + addr) = z;
    }
    // stage input rows (wave w -> LDS row w)
    {
        int r = wid;
        int y_in = y0 - 1 + r;
        if ((unsigned)y_in < 56u) {
            const int8_t* src = b8T + ((size_t)(b * 3136 + y_in * 56)) * 128;
            for (int it = 0; it < 7; it++) {
                i32x4 v = *(const i32x4*)(src + it * 1024 + lane * 16);
                *(i32x4*)(lds + r * 8192 + 128 + it * 1024 + lane * 16) = v;
            }
        } else {
            i32x4 z = {0, 0, 0, 0};
            for (int it = 0; it < 8; it++)
                *(i32x4*)(lds + r * 8192 + it * 1024 + lane * 16) = z;
        }
    }
    __syncthreads();

    int m = wid & 1, r_out = wid >> 1;
    int o_base = m * 16;
    // preload A fragments: lane holds A[o=o_base+(lane&15)][k=(lane>>4)*16 + j]
    i32x4 afr[18];
    const int8_t* abase = w8A + (size_t)(o_base + (lane & 15)) * 1152 + (lane >> 4) * 16;
    #pragma unroll
    for (int ks = 0; ks < 18; ks++)
        afr[ks] = *(const i32x4*)(abase + ks * 64);

    i32x4 acc[4];
    #pragma unroll
    for (int nt = 0; nt < 4; nt++) acc[nt] = (i32x4){0, 0, 0, 0};
    int c_lane = (lane >> 4) * 16;
    int xl = lane & 15;

    #pragma unroll
    for (int ks = 0; ks < 18; ks++) {
        int dy = ks / 6, rest = ks % 6;
        int dx = rest >> 1, c0 = (rest & 1) * 64;
        int r = r_out + dy;
        #pragma unroll
        for (int nt = 0; nt < 4; nt++) {
            int x_out = nt * 16 + xl;
            int xp = x_out + dx; if (xp > 63) xp = 63;
            int caddr = (c0 + c_lane) ^ ((xp & 7) << 4);
            i32x4 bfr = *(const i32x4*)(lds + r * 8192 + xp * 128 + caddr);
            acc[nt] = __builtin_amdgcn_mfma_i32_16x16x64_i8(afr[ks], bfr, acc[nt], 0, 0, 0);
        }
    }

    // epilogue: C/D layout col=lane&15 (pixel), row=(lane>>4)*4+reg (o)
    float s_out = soutp[0];
    int orow = o_base + ((lane >> 4) << 2);
    float sc[4];
    #pragma unroll
    for (int reg = 0; reg < 4; reg++) sc[reg] = sC[orow + reg];
    int y = y0 + r_out;
    size_t outb = ((size_t)b * 288 + 256 + orow) * 3136 + (size_t)y * 56;
    #pragma unroll
    for (int nt = 0; nt < 4; nt++) {
        int x_out = nt * 16 + xl;
        if (x_out < 56) {
            #pragma unroll
            for (int reg = 0; reg < 4; reg++) {
                float xf = __fmul_rn((float)acc[nt][reg], sc[reg]);
                float q = __fdiv_rn(xf, s_out);
                float val = __fmul_rn(clip127(rintf(q)), s_out);
                out[outb + (size_t)reg * 3136 + x_out] = val;
            }
        }
    }
}

extern "C" void kernel_launch(void* const* d_in, const int* in_sizes, int n_in,
                              void* d_out, int out_size, void* d_ws, size_t ws_size,
                              hipStream_t stream) {
    const float* batch = (const float*)d_in[0];
    const float* s_in  = (const float*)d_in[1];
    const float* bn1g  = (const float*)d_in[2];
    const float* bn1b  = (const float*)d_in[3];
    const float* bn1m  = (const float*)d_in[4];
    const float* bn1v  = (const float*)d_in[5];
    const float* w1    = (const float*)d_in[6];
    const float* bn2g  = (const float*)d_in[7];
    const float* bn2b  = (const float*)d_in[8];
    const float* bn2m  = (const float*)d_in[9];
    const float* bn2v  = (const float*)d_in[10];
    const float* w2    = (const float*)d_in[11];
    const float* s1    = (const float*)d_in[12];
    const float* s2    = (const float*)d_in[13];
    const float* s_out = (const float*)d_in[14];
    float* out = (float*)d_out;
    char* ws = (char*)d_ws;

    int8_t* a8   = (int8_t*)ws;                     // 25,690,112 B
    int8_t* b8T  = (int8_t*)(ws + 25690112);        // 12,845,056 B (swizzled NHWC)
    int8_t* w1i8 = (int8_t*)(ws + 38535168);        // 32,768 B
    int8_t* w8A  = (int8_t*)(ws + 38567936);        // 36,864 B
    float* wA    = (float*)(ws + 38604800);         // 1 KB
    float* bA    = (float*)(ws + 38605824);         // 1 KB
    float* b1    = (float*)(ws + 38606848);         // 512 B
    float* sB    = (float*)(ws + 38607360);         // 512 B
    float* sC    = (float*)(ws + 38607872);         // 128 B
    float* misc  = (float*)(ws + 38608000);         // 64 B

    prep1<<<1, 256, 0, stream>>>(bn1g, bn1b, bn1m, bn1v, s_in, s_out, wA, bA, misc, out, out_size - 1);
    prep2<<<128, 256, 0, stream>>>(bn2g, bn2b, bn2m, bn2v, w1, s1, w1i8, b1, sB);
    prep3<<<32, 256, 0, stream>>>(w2, s2, w8A, sC);
    stageA<<<25088, 256, 0, stream>>>(batch, s_in, s1, s_out, wA, bA, misc, a8, out);
    conv1k<<<1568, 256, 0, stream>>>(a8, w1i8, b1, sB, s2, b8T);
    conv2k<<<896, 256, 0, stream>>>(b8T, w8A, sC, s_out, out);
}

// Round 17
// 87.548 us; speedup vs baseline: 13.9848x; 1.2458x over previous
//
#include <hip/hip_runtime.h>
#include <stdint.h>

#define EPSF 1e-5f

// problem sizes
#define NB 32
#define NC 256
#define NMID 128
#define NGROW 32
#define HW 3136      // 56*56
#define WD 56
#define BCHW 25690112   // 32*256*3136
#define BMHW 12845056   // 32*128*3136

typedef int i32x4 __attribute__((ext_vector_type(4)));

__device__ __forceinline__ float clip127(float v) {
    return fminf(fmaxf(v, -128.f), 127.f);
}

// ---------------- prep kernels ----------------
__global__ void prep1(const float* __restrict__ g, const float* __restrict__ be,
                      const float* __restrict__ mn, const float* __restrict__ vr,
                      const float* __restrict__ s_in_p, const float* __restrict__ s_out_p,
                      float* __restrict__ wA, float* __restrict__ bA, float* __restrict__ misc,
                      float* __restrict__ out, int out_last) {
    __shared__ float red[256];
    int t = threadIdx.x;
    float s_in = s_in_p[0];
    float w = __fmul_rn(g[t], __frsqrt_rn(__fadd_rn(vr[t], EPSF)));
    float bb = __fsub_rn(be[t], __fmul_rn(mn[t], w));
    red[t] = fabsf(w);
    __syncthreads();
    for (int s = 128; s > 0; s >>= 1) { if (t < s) red[t] = fmaxf(red[t], red[t + s]); __syncthreads(); }
    float ws = __fdiv_rn(red[0], 127.f);
    wA[t] = clip127(rintf(__fdiv_rn(w, ws)));
    float sA = __fmul_rn(ws, s_in);
    bA[t] = rintf(__fdiv_rn(bb, sA));
    if (t == 0) { misc[0] = sA; out[out_last] = s_out_p[0]; }
}

// conv1 weights folded with bn2 -> int8 row-major w1i8[m][c], bias b1, scale sB
__global__ void prep2(const float* __restrict__ g, const float* __restrict__ be,
                      const float* __restrict__ mn, const float* __restrict__ vr,
                      const float* __restrict__ w1, const float* __restrict__ s1_p,
                      int8_t* __restrict__ w1i8, float* __restrict__ b1, float* __restrict__ sB) {
    __shared__ float red[256];
    int t = threadIdx.x, m = blockIdx.x;
    float f = __fmul_rn(g[m], __frsqrt_rn(__fadd_rn(vr[m], EPSF)));
    float wf = __fmul_rn(w1[m * 256 + t], f);
    red[t] = fabsf(wf);
    __syncthreads();
    for (int s = 128; s > 0; s >>= 1) { if (t < s) red[t] = fmaxf(red[t], red[t + s]); __syncthreads(); }
    float ws = __fdiv_rn(red[0], 127.f);
    float q = clip127(rintf(__fdiv_rn(wf, ws)));
    w1i8[m * 256 + t] = (int8_t)(int)q;
    if (t == 0) {
        float s1 = s1_p[0];
        float bf = __fsub_rn(be[m], __fmul_rn(mn[m], f));
        float sb = __fmul_rn(ws, s1);
        b1[m] = rintf(__fdiv_rn(bf, sb));
        sB[m] = sb;
    }
}

// weights for conv2, int8, tap-major K layout: w8A[o][tap*128 + c]
__global__ void prep3(const float* __restrict__ w2, const float* __restrict__ s2_p,
                      int8_t* __restrict__ w8A, float* __restrict__ sC) {
    __shared__ float red[256];
    int t = threadIdx.x, o = blockIdx.x;
    float mx = 0.f;
    for (int k = t; k < 1152; k += 256) mx = fmaxf(mx, fabsf(w2[o * 1152 + k]));
    red[t] = mx;
    __syncthreads();
    for (int s = 128; s > 0; s >>= 1) { if (t < s) red[t] = fmaxf(red[t], red[t + s]); __syncthreads(); }
    float ws = __fdiv_rn(red[0], 127.f);
    for (int k = t; k < 1152; k += 256) {
        int c = k / 9, tap = k % 9;
        float q = clip127(rintf(__fdiv_rn(w2[o * 1152 + k], ws)));
        w8A[o * 1152 + tap * 128 + c] = (int8_t)(int)q;
    }
    if (t == 0) sC[o] = __fmul_rn(ws, s2_p[0]);
}

// ---------------- fusedA: BN quant + passthrough + conv1 (1x1 int8 MFMA) -----
// Block = (b, 64-px tile). Reads batch f32 channel-major, quantizes inline to
// swizzled pixel-major LDS [64 px][256 c] (c ^ ((px&15)<<4)), writes the
// passthrough out channels, then conv1 MFMA from LDS.
// Output b8T[(b*3136 + hw)*128 + (m ^ sw(x))], sw(x) = (((x+1)&7)<<4).
__global__ __launch_bounds__(256) void fusedA(const float* __restrict__ batch,
        const float* __restrict__ sfp, const float* __restrict__ s1p, const float* __restrict__ soutp,
        const float* __restrict__ s2p,
        const float* __restrict__ wAp, const float* __restrict__ bAp, const float* __restrict__ misc,
        const int8_t* __restrict__ w1i8, const float* __restrict__ b1, const float* __restrict__ sB,
        float* __restrict__ out, int8_t* __restrict__ b8T) {
    __shared__ __align__(16) int8_t lds[64 * 256];   // 16 KB
    int t = threadIdx.x;
    int blk = blockIdx.x;          // 32 b * 49 tiles
    int b = blk / 49, tile = blk % 49;
    int hw0 = tile * 64;

    float s_in = sfp[0], s1 = s1p[0], s_out = soutp[0], sA = misc[0];

    // stage: read batch channel-major (coalesced float4), BN-quant to int8,
    // byte-scatter to pixel-major swizzled LDS; write passthrough out.
    #pragma unroll 4
    for (int it = 0; it < 16; it++) {
        int c = it * 16 + (t >> 4);
        int p4 = (t & 15) * 4;
        float wc = wAp[c], bc = bAp[c];
        float4 v = *(const float4*)(batch + (size_t)(b * 256 + c) * 3136 + hw0 + p4);
        float vv[4] = {v.x, v.y, v.z, v.w};
        float ov[4];
        #pragma unroll
        for (int j = 0; j < 4; j++) {
            float xi = __fdiv_rn(vv[j], s_in);
            float tt = __fadd_rn(__fmul_rn(xi, wc), bc);
            float x = __fmul_rn(tt, sA);
            x = fmaxf(x, 0.f);
            float q = __fdiv_rn(x, s1);
            int ai = (int)clip127(rintf(q));
            int px = p4 + j;
            lds[px * 256 + (c ^ ((px & 15) << 4))] = (int8_t)ai;
            float qo = __fdiv_rn(vv[j], s_out);
            ov[j] = __fmul_rn(clip127(rintf(qo)), s_out);
        }
        *(float4*)(out + (size_t)(b * 288 + c) * 3136 + hw0 + p4) =
            make_float4(ov[0], ov[1], ov[2], ov[3]);
    }
    __syncthreads();

    int wid = t >> 6, lane = t & 63;
    int px_base = wid * 16;
    int px = px_base + (lane & 15);
    int ksl = (lane >> 4);                 // k-slice within MFMA (0..3), 16 bytes each

    // B fragments: 16 px x 256 K, per wave (held in regs, read once)
    i32x4 bf[4];
    #pragma unroll
    for (int kk = 0; kk < 4; kk++) {
        int coff = (kk * 64 + ksl * 16) ^ ((px & 15) << 4);
        bf[kk] = *(const i32x4*)(lds + px * 256 + coff);
    }

    float s2 = s2p[0];
    int hw = hw0 + px;
    int x = hw - (hw / 56) * 56;
    int sw = (((x + 1) & 7) << 4);
    size_t outrow = (size_t)(b * 3136 + hw) * 128;

    #pragma unroll
    for (int ot = 0; ot < 8; ot++) {
        // A fragments: weights for o = ot*16 + (lane&15), K contiguous
        const int8_t* wb = w1i8 + (size_t)(ot * 16 + (lane & 15)) * 256 + ksl * 16;
        i32x4 acc = (i32x4){0, 0, 0, 0};
        #pragma unroll
        for (int kk = 0; kk < 4; kk++) {
            i32x4 af = *(const i32x4*)(wb + kk * 64);
            acc = __builtin_amdgcn_mfma_i32_16x16x64_i8(af, bf[kk], acc, 0, 0, 0);
        }
        // epilogue: lane holds px (col) x o rows m0..m0+3
        int m0 = ot * 16 + ksl * 4;
        uint32_t pk = 0;
        #pragma unroll
        for (int reg = 0; reg < 4; reg++) {
            float y = __fadd_rn((float)acc[reg], b1[m0 + reg]);
            float xq = __fmul_rn(y, sB[m0 + reg]);
            xq = fmaxf(xq, 0.f);
            float q = __fdiv_rn(xq, s2);
            int bi = (int)clip127(rintf(q));
            pk |= ((uint32_t)(uint8_t)bi) << (8 * reg);
        }
        *(uint32_t*)(b8T + outrow + (size_t)(m0 ^ sw)) = pk;
    }
}

// ---------------- conv2: 3x3 SAME, 128->32, int8 MFMA implicit GEMM ----------
// block: 2 output rows x 32 o x 56 px. LDS [4 rows][64 x'][128 c] int8, x'=x_in+1,
// swizzled c-offset (c ^ ((x'&7)<<4)) baked into b8T by fusedA.
__global__ __launch_bounds__(256) void conv2k(const int8_t* __restrict__ b8T,
        const int8_t* __restrict__ w8A, const float* __restrict__ sC,
        const float* __restrict__ soutp, float* __restrict__ out) {
    __shared__ __align__(16) int8_t lds[4 * 64 * 128];   // 32 KB
    int t = threadIdx.x;
    int blk = blockIdx.x;               // 32 b * 28 ytiles
    int b = blk / 28, tile = blk % 28;
    int y0 = tile * 2;
    int wid = t >> 6, lane = t & 63;

    // zero edge columns: x'=0 and x'=57..63, all 4 rows
    {
        int r = wid, idx = lane;
        i32x4 z = {0, 0, 0, 0};
        int addr;
        if (idx < 8) addr = r * 8192 + idx * 16;
        else {
            int xp = 57 + (idx - 8) / 8, sub = (idx - 8) & 7;
            addr = r * 8192 + xp * 128 + sub * 16;
        }
        *(i32x4*)(lds + addr) = z;
    }
    // stage input rows (wave w -> LDS row w)
    {
        int r = wid;
        int y_in = y0 - 1 + r;
        if ((unsigned)y_in < 56u) {
            const int8_t* src = b8T + ((size_t)(b * 3136 + y_in * 56)) * 128;
            for (int it = 0; it < 7; it++) {
                i32x4 v = *(const i32x4*)(src + it * 1024 + lane * 16);
                *(i32x4*)(lds + r * 8192 + 128 + it * 1024 + lane * 16) = v;
            }
        } else {
            i32x4 z = {0, 0, 0, 0};
            for (int it = 0; it < 8; it++)
                *(i32x4*)(lds + r * 8192 + it * 1024 + lane * 16) = z;
        }
    }
    __syncthreads();

    int m = wid & 1, r_out = wid >> 1;
    int o_base = m * 16;
    // preload A fragments: lane holds A[o=o_base+(lane&15)][k=(lane>>4)*16 + j]
    i32x4 afr[18];
    const int8_t* abase = w8A + (size_t)(o_base + (lane & 15)) * 1152 + (lane >> 4) * 16;
    #pragma unroll
    for (int ks = 0; ks < 18; ks++)
        afr[ks] = *(const i32x4*)(abase + ks * 64);

    i32x4 acc[4];
    #pragma unroll
    for (int nt = 0; nt < 4; nt++) acc[nt] = (i32x4){0, 0, 0, 0};
    int c_lane = (lane >> 4) * 16;
    int xl = lane & 15;

    #pragma unroll
    for (int ks = 0; ks < 18; ks++) {
        int dy = ks / 6, rest = ks % 6;
        int dx = rest >> 1, c0 = (rest & 1) * 64;
        int r = r_out + dy;
        #pragma unroll
        for (int nt = 0; nt < 4; nt++) {
            int x_out = nt * 16 + xl;
            int xp = x_out + dx; if (xp > 63) xp = 63;
            int caddr = (c0 + c_lane) ^ ((xp & 7) << 4);
            i32x4 bfr = *(const i32x4*)(lds + r * 8192 + xp * 128 + caddr);
            acc[nt] = __builtin_amdgcn_mfma_i32_16x16x64_i8(afr[ks], bfr, acc[nt], 0, 0, 0);
        }
    }

    // epilogue: C/D layout col=lane&15 (pixel), row=(lane>>4)*4+reg (o)
    float s_out = soutp[0];
    int orow = o_base + ((lane >> 4) << 2);
    float sc[4];
    #pragma unroll
    for (int reg = 0; reg < 4; reg++) sc[reg] = sC[orow + reg];
    int y = y0 + r_out;
    size_t outb = ((size_t)b * 288 + 256 + orow) * 3136 + (size_t)y * 56;
    #pragma unroll
    for (int nt = 0; nt < 4; nt++) {
        int x_out = nt * 16 + xl;
        if (x_out < 56) {
            #pragma unroll
            for (int reg = 0; reg < 4; reg++) {
                float xf = __fmul_rn((float)acc[nt][reg], sc[reg]);
                float q = __fdiv_rn(xf, s_out);
                float val = __fmul_rn(clip127(rintf(q)), s_out);
                out[outb + (size_t)reg * 3136 + x_out] = val;
            }
        }
    }
}

extern "C" void kernel_launch(void* const* d_in, const int* in_sizes, int n_in,
                              void* d_out, int out_size, void* d_ws, size_t ws_size,
                              hipStream_t stream) {
    const float* batch = (const float*)d_in[0];
    const float* s_in  = (const float*)d_in[1];
    const float* bn1g  = (const float*)d_in[2];
    const float* bn1b  = (const float*)d_in[3];
    const float* bn1m  = (const float*)d_in[4];
    const float* bn1v  = (const float*)d_in[5];
    const float* w1    = (const float*)d_in[6];
    const float* bn2g  = (const float*)d_in[7];
    const float* bn2b  = (const float*)d_in[8];
    const float* bn2m  = (const float*)d_in[9];
    const float* bn2v  = (const float*)d_in[10];
    const float* w2    = (const float*)d_in[11];
    const float* s1    = (const float*)d_in[12];
    const float* s2    = (const float*)d_in[13];
    const float* s_out = (const float*)d_in[14];
    float* out = (float*)d_out;
    char* ws = (char*)d_ws;

    int8_t* b8T  = (int8_t*)ws;                     // 12,845,056 B (swizzled NHWC)
    int8_t* w1i8 = (int8_t*)(ws + 12845056);        // 32,768 B
    int8_t* w8A  = (int8_t*)(ws + 12877824);        // 36,864 B
    float* wA    = (float*)(ws + 12914688);         // 1 KB
    float* bA    = (float*)(ws + 12915712);         // 1 KB
    float* b1    = (float*)(ws + 12916736);         // 512 B
    float* sB    = (float*)(ws + 12917248);         // 512 B
    float* sC    = (float*)(ws + 12917760);         // 128 B
    float* misc  = (float*)(ws + 12917888);         // 64 B

    prep1<<<1, 256, 0, stream>>>(bn1g, bn1b, bn1m, bn1v, s_in, s_out, wA, bA, misc, out, out_size - 1);
    prep2<<<128, 256, 0, stream>>>(bn2g, bn2b, bn2m, bn2v, w1, s1, w1i8, b1, sB);
    prep3<<<32, 256, 0, stream>>>(w2, s2, w8A, sC);
    fusedA<<<1568, 256, 0, stream>>>(batch, s_in, s1, s_out, s2, wA, bA, misc,
                                     w1i8, b1, sB, out, b8T);
    conv2k<<<896, 256, 0, stream>>>(b8T, w8A, sC, s_out, out);
}

// Round 18
// 87.148 us; speedup vs baseline: 14.0489x; 1.0046x over previous
//
#include <hip/hip_runtime.h>
#include <stdint.h>

#define EPSF 1e-5f

// problem sizes
#define NB 32
#define NC 256
#define NMID 128
#define NGROW 32
#define HW 3136      // 56*56
#define WD 56
#define BCHW 25690112   // 32*256*3136
#define BMHW 12845056   // 32*128*3136

typedef int i32x4 __attribute__((ext_vector_type(4)));

__device__ __forceinline__ float clip127(float v) {
    return fminf(fmaxf(v, -128.f), 127.f);
}

// ---------------- prep kernels ----------------
__global__ void prep1(const float* __restrict__ g, const float* __restrict__ be,
                      const float* __restrict__ mn, const float* __restrict__ vr,
                      const float* __restrict__ s_in_p, const float* __restrict__ s_out_p,
                      float* __restrict__ wA, float* __restrict__ bA, float* __restrict__ misc,
                      float* __restrict__ out, int out_last) {
    __shared__ float red[256];
    int t = threadIdx.x;
    float s_in = s_in_p[0];
    float w = __fmul_rn(g[t], __frsqrt_rn(__fadd_rn(vr[t], EPSF)));
    float bb = __fsub_rn(be[t], __fmul_rn(mn[t], w));
    red[t] = fabsf(w);
    __syncthreads();
    for (int s = 128; s > 0; s >>= 1) { if (t < s) red[t] = fmaxf(red[t], red[t + s]); __syncthreads(); }
    float ws = __fdiv_rn(red[0], 127.f);
    wA[t] = clip127(rintf(__fdiv_rn(w, ws)));
    float sA = __fmul_rn(ws, s_in);
    bA[t] = rintf(__fdiv_rn(bb, sA));
    if (t == 0) { misc[0] = sA; out[out_last] = s_out_p[0]; }
}

// conv1 weights folded with bn2 -> int8 row-major w1i8[m][c], bias b1, scale sB
__global__ void prep2(const float* __restrict__ g, const float* __restrict__ be,
                      const float* __restrict__ mn, const float* __restrict__ vr,
                      const float* __restrict__ w1, const float* __restrict__ s1_p,
                      int8_t* __restrict__ w1i8, float* __restrict__ b1, float* __restrict__ sB) {
    __shared__ float red[256];
    int t = threadIdx.x, m = blockIdx.x;
    float f = __fmul_rn(g[m], __frsqrt_rn(__fadd_rn(vr[m], EPSF)));
    float wf = __fmul_rn(w1[m * 256 + t], f);
    red[t] = fabsf(wf);
    __syncthreads();
    for (int s = 128; s > 0; s >>= 1) { if (t < s) red[t] = fmaxf(red[t], red[t + s]); __syncthreads(); }
    float ws = __fdiv_rn(red[0], 127.f);
    float q = clip127(rintf(__fdiv_rn(wf, ws)));
    w1i8[m * 256 + t] = (int8_t)(int)q;
    if (t == 0) {
        float s1 = s1_p[0];
        float bf = __fsub_rn(be[m], __fmul_rn(mn[m], f));
        float sb = __fmul_rn(ws, s1);
        b1[m] = rintf(__fdiv_rn(bf, sb));
        sB[m] = sb;
    }
}

// weights for conv2, int8, tap-major K layout: w8A[o][tap*128 + c]
__global__ void prep3(const float* __restrict__ w2, const float* __restrict__ s2_p,
                      int8_t* __restrict__ w8A, float* __restrict__ sC) {
    __shared__ float red[256];
    int t = threadIdx.x, o = blockIdx.x;
    float mx = 0.f;
    for (int k = t; k < 1152; k += 256) mx = fmaxf(mx, fabsf(w2[o * 1152 + k]));
    red[t] = mx;
    __syncthreads();
    for (int s = 128; s > 0; s >>= 1) { if (t < s) red[t] = fmaxf(red[t], red[t + s]); __syncthreads(); }
    float ws = __fdiv_rn(red[0], 127.f);
    for (int k = t; k < 1152; k += 256) {
        int c = k / 9, tap = k % 9;
        float q = clip127(rintf(__fdiv_rn(w2[o * 1152 + k], ws)));
        w8A[o * 1152 + tap * 128 + c] = (int8_t)(int)q;
    }
    if (t == 0) sC[o] = __fmul_rn(ws, s2_p[0]);
}

// ---------------- fusedA: BN quant + passthrough + conv1 (1x1 int8 MFMA) -----
// Lane owns one pixel (pxl = t&63); wave w covers channels w*64..w*64+63.
// Per-channel scalar loads are coalesced across lanes (64 consecutive px).
// LDS layout [cb][px][16] int8 (cb = c>>4): dense ds_write_b128, no swizzle.
// Output b8T[(b*3136 + hw)*128 + (m ^ sw(x))], sw(x) = (((x+1)&7)<<4).
__global__ __launch_bounds__(256) void fusedA(const float* __restrict__ batch,
        const float* __restrict__ sfp, const float* __restrict__ s1p, const float* __restrict__ soutp,
        const float* __restrict__ s2p,
        const float* __restrict__ wAp, const float* __restrict__ bAp, const float* __restrict__ misc,
        const int8_t* __restrict__ w1i8, const float* __restrict__ b1, const float* __restrict__ sB,
        float* __restrict__ out, int8_t* __restrict__ b8T) {
    __shared__ __align__(16) int8_t lds[16 * 64 * 16];   // [cb][px][16] = 16 KB
    int t = threadIdx.x;
    int blk = blockIdx.x;          // 32 b * 49 tiles
    int b = blk / 49, tile = blk % 49;
    int hw0 = tile * 64;
    int pxl = t & 63, w = t >> 6;

    float s_in = sfp[0], s1 = s1p[0], s_out = soutp[0], sA = misc[0];

    const float* bb_base = batch + (size_t)b * 802816 + hw0 + pxl;
    float* ob_base = out + (size_t)b * 288 * 3136 + hw0 + pxl;

    #pragma unroll
    for (int i16 = 0; i16 < 4; i16++) {
        int cb = w * 4 + i16;
        uint32_t r0 = 0, r1 = 0, r2 = 0, r3 = 0;
        #pragma unroll
        for (int s = 0; s < 4; s++) {
            uint32_t pk = 0;
            #pragma unroll
            for (int k = 0; k < 4; k++) {
                int c = cb * 16 + s * 4 + k;
                float v = bb_base[(size_t)c * 3136];
                float wc = wAp[c], bc = bAp[c];     // wave-uniform -> s_load
                float xi = __fdiv_rn(v, s_in);
                float tt = __fadd_rn(__fmul_rn(xi, wc), bc);
                float x = __fmul_rn(tt, sA);
                x = fmaxf(x, 0.f);
                float q = __fdiv_rn(x, s1);
                int ai = (int)clip127(rintf(q));
                pk |= ((uint32_t)(uint8_t)ai) << (8 * k);
                float qo = __fdiv_rn(v, s_out);
                ob_base[(size_t)c * 3136] = __fmul_rn(clip127(rintf(qo)), s_out);
            }
            if (s == 0) r0 = pk; else if (s == 1) r1 = pk;
            else if (s == 2) r2 = pk; else r3 = pk;
        }
        i32x4 wv;
        wv[0] = (int)r0; wv[1] = (int)r1; wv[2] = (int)r2; wv[3] = (int)r3;
        *(i32x4*)(lds + cb * 1024 + pxl * 16) = wv;   // dense, conflict-free
    }
    __syncthreads();

    int wid = w, lane = t & 63;
    int px = wid * 16 + (lane & 15);
    int ksl = (lane >> 4);                 // k-slice within MFMA (0..3), 16 bytes each

    // B fragments: 16 px x 256 K per wave; bf[kk] = channels kk*64+ksl*16 .. +15
    i32x4 bf[4];
    #pragma unroll
    for (int kk = 0; kk < 4; kk++)
        bf[kk] = *(const i32x4*)(lds + (kk * 4 + ksl) * 1024 + px * 16);

    float s2 = s2p[0];
    int hw = hw0 + px;
    int x = hw - (hw / 56) * 56;
    int sw = (((x + 1) & 7) << 4);
    size_t outrow = (size_t)(b * 3136 + hw) * 128;

    #pragma unroll
    for (int ot = 0; ot < 8; ot++) {
        // A fragments: weights for o = ot*16 + (lane&15), K contiguous
        const int8_t* wb = w1i8 + (size_t)(ot * 16 + (lane & 15)) * 256 + ksl * 16;
        i32x4 acc = (i32x4){0, 0, 0, 0};
        #pragma unroll
        for (int kk = 0; kk < 4; kk++) {
            i32x4 af = *(const i32x4*)(wb + kk * 64);
            acc = __builtin_amdgcn_mfma_i32_16x16x64_i8(af, bf[kk], acc, 0, 0, 0);
        }
        // epilogue: lane holds px (col) x o rows m0..m0+3
        int m0 = ot * 16 + ksl * 4;
        uint32_t pk = 0;
        #pragma unroll
        for (int reg = 0; reg < 4; reg++) {
            float y = __fadd_rn((float)acc[reg], b1[m0 + reg]);
            float xq = __fmul_rn(y, sB[m0 + reg]);
            xq = fmaxf(xq, 0.f);
            float q = __fdiv_rn(xq, s2);
            int bi = (int)clip127(rintf(q));
            pk |= ((uint32_t)(uint8_t)bi) << (8 * reg);
        }
        *(uint32_t*)(b8T + outrow + (size_t)(m0 ^ sw)) = pk;
    }
}

// ---------------- conv2: 3x3 SAME, 128->32, int8 MFMA implicit GEMM ----------
// block: 2 output rows x 32 o x 56 px. LDS [4 rows][64 x'][128 c] int8, x'=x_in+1,
// swizzled c-offset (c ^ ((x'&7)<<4)) baked into b8T by fusedA.
__global__ __launch_bounds__(256) void conv2k(const int8_t* __restrict__ b8T,
        const int8_t* __restrict__ w8A, const float* __restrict__ sC,
        const float* __restrict__ soutp, float* __restrict__ out) {
    __shared__ __align__(16) int8_t lds[4 * 64 * 128];   // 32 KB
    int t = threadIdx.x;
    int blk = blockIdx.x;               // 32 b * 28 ytiles
    int b = blk / 28, tile = blk % 28;
    int y0 = tile * 2;
    int wid = t >> 6, lane = t & 63;

    // zero edge columns: x'=0 and x'=57..63, all 4 rows
    {
        int r = wid, idx = lane;
        i32x4 z = {0, 0, 0, 0};
        int addr;
        if (idx < 8) addr = r * 8192 + idx * 16;
        else {
            int xp = 57 + (idx - 8) / 8, sub = (idx - 8) & 7;
            addr = r * 8192 + xp * 128 + sub * 16;
        }
        *(i32x4*)(lds + addr) = z;
    }
    // stage input rows (wave w -> LDS row w)
    {
        int r = wid;
        int y_in = y0 - 1 + r;
        if ((unsigned)y_in < 56u) {
            const int8_t* src = b8T + ((size_t)(b * 3136 + y_in * 56)) * 128;
            for (int it = 0; it < 7; it++) {
                i32x4 v = *(const i32x4*)(src + it * 1024 + lane * 16);
                *(i32x4*)(lds + r * 8192 + 128 + it * 1024 + lane * 16) = v;
            }
        } else {
            i32x4 z = {0, 0, 0, 0};
            for (int it = 0; it < 8; it++)
                *(i32x4*)(lds + r * 8192 + it * 1024 + lane * 16) = z;
        }
    }
    __syncthreads();

    int m = wid & 1, r_out = wid >> 1;
    int o_base = m * 16;
    // preload A fragments: lane holds A[o=o_base+(lane&15)][k=(lane>>4)*16 + j]
    i32x4 afr[18];
    const int8_t* abase = w8A + (size_t)(o_base + (lane & 15)) * 1152 + (lane >> 4) * 16;
    #pragma unroll
    for (int ks = 0; ks < 18; ks++)
        afr[ks] = *(const i32x4*)(abase + ks * 64);

    i32x4 acc[4];
    #pragma unroll
    for (int nt = 0; nt < 4; nt++) acc[nt] = (i32x4){0, 0, 0, 0};
    int c_lane = (lane >> 4) * 16;
    int xl = lane & 15;

    #pragma unroll
    for (int ks = 0; ks < 18; ks++) {
        int dy = ks / 6, rest = ks % 6;
        int dx = rest >> 1, c0 = (rest & 1) * 64;
        int r = r_out + dy;
        #pragma unroll
        for (int nt = 0; nt < 4; nt++) {
            int x_out = nt * 16 + xl;
            int xp = x_out + dx; if (xp > 63) xp = 63;
            int caddr = (c0 + c_lane) ^ ((xp & 7) << 4);
            i32x4 bfr = *(const i32x4*)(lds + r * 8192 + xp * 128 + caddr);
            acc[nt] = __builtin_amdgcn_mfma_i32_16x16x64_i8(afr[ks], bfr, acc[nt], 0, 0, 0);
        }
    }

    // epilogue: C/D layout col=lane&15 (pixel), row=(lane>>4)*4+reg (o)
    float s_out = soutp[0];
    int orow = o_base + ((lane >> 4) << 2);
    float sc[4];
    #pragma unroll
    for (int reg = 0; reg < 4; reg++) sc[reg] = sC[orow + reg];
    int y = y0 + r_out;
    size_t outb = ((size_t)b * 288 + 256 + orow) * 3136 + (size_t)y * 56;
    #pragma unroll
    for (int nt = 0; nt < 4; nt++) {
        int x_out = nt * 16 + xl;
        if (x_out < 56) {
            #pragma unroll
            for (int reg = 0; reg < 4; reg++) {
                float xf = __fmul_rn((float)acc[nt][reg], sc[reg]);
                float q = __fdiv_rn(xf, s_out);
                float val = __fmul_rn(clip127(rintf(q)), s_out);
                out[outb + (size_t)reg * 3136 + x_out] = val;
            }
        }
    }
}

extern "C" void kernel_launch(void* const* d_in, const int* in_sizes, int n_in,
                              void* d_out, int out_size, void* d_ws, size_t ws_size,
                              hipStream_t stream) {
    const float* batch = (const float*)d_in[0];
    const float* s_in  = (const float*)d_in[1];
    const float* bn1g  = (const float*)d_in[2];
    const float* bn1b  = (const float*)d_in[3];
    const float* bn1m  = (const float*)d_in[4];
    const float* bn1v  = (const float*)d_in[5];
    const float* w1    = (const float*)d_in[6];
    const float* bn2g  = (const float*)d_in[7];
    const float* bn2b  = (const float*)d_in[8];
    const float* bn2m  = (const float*)d_in[9];
    const float* bn2v  = (const float*)d_in[10];
    const float* w2    = (const float*)d_in[11];
    const float* s1    = (const float*)d_in[12];
    const float* s2    = (const float*)d_in[13];
    const float* s_out = (const float*)d_in[14];
    float* out = (float*)d_out;
    char* ws = (char*)d_ws;

    int8_t* b8T  = (int8_t*)ws;                     // 12,845,056 B (swizzled NHWC)
    int8_t* w1i8 = (int8_t*)(ws + 12845056);        // 32,768 B
    int8_t* w8A  = (int8_t*)(ws + 12877824);        // 36,864 B
    float* wA    = (float*)(ws + 12914688);         // 1 KB
    float* bA    = (float*)(ws + 12915712);         // 1 KB
    float* b1    = (float*)(ws + 12916736);         // 512 B
    float* sB    = (float*)(ws + 12917248);         // 512 B
    float* sC    = (float*)(ws + 12917760);         // 128 B
    float* misc  = (float*)(ws + 12917888);         // 64 B

    prep1<<<1, 256, 0, stream>>>(bn1g, bn1b, bn1m, bn1v, s_in, s_out, wA, bA, misc, out, out_size - 1);
    prep2<<<128, 256, 0, stream>>>(bn2g, bn2b, bn2m, bn2v, w1, s1, w1i8, b1, sB);
    prep3<<<32, 256, 0, stream>>>(w2, s2, w8A, sC);
    fusedA<<<1568, 256, 0, stream>>>(batch, s_in, s1, s_out, s2, wA, bA, misc,
                                     w1i8, b1, sB, out, b8T);
    conv2k<<<896, 256, 0, stream>>>(b8T, w8A, sC, s_out, out);
}